// Round 5
// baseline (112.876 us; speedup 1.0000x reference)
//
#include <hip/hip_runtime.h>

// GAT: B=4, N=2048, IN_DIM=128, H=4, D=64.
// R5: attn PV via 32x32x16 MFMA (128-row i-tiles, 2 C-tiles/wave, halved B-frag
// LDS traffic, shuffle-free l via ones-MFMA in matching C layout); adj_pack
// fused into gat_linear (one fewer dispatch).

#define NDIM 2048
#define NEG_SLOPE 0.2f
#define LOG2E 1.4426950408889634f

typedef __bf16 bf16x8 __attribute__((ext_vector_type(8)));
typedef __bf16 bf16x4 __attribute__((ext_vector_type(4)));
typedef float  f32x4  __attribute__((ext_vector_type(4)));
typedef float  f32x16 __attribute__((ext_vector_type(16)));

#define LP 136   // linear LDS pitch (bf16)

__device__ static inline void load_lds16(const void* g, void* l) {
    __builtin_amdgcn_global_load_lds(
        (const __attribute__((address_space(1))) unsigned*)g,
        (__attribute__((address_space(3))) unsigned*)l, 16, 0, 0);
}

// ---------------- linear (+ fused adj bit-pack) ----------------
// grid 512: blk = head(4) x ntile(128 of 64 n). Also packs 32 KB of adj.
__global__ __launch_bounds__(256) void gat_linear(
    const float* __restrict__ x, const float* __restrict__ W,
    const float* __restrict__ att_src, const float* __restrict__ att_dst,
    const int* __restrict__ adj, unsigned* __restrict__ bits,
    __bf16* __restrict__ h_t, float* __restrict__ es_ws, float* __restrict__ ed_ws)
{
    const int t    = threadIdx.x;
    const int head = blockIdx.x & 3;
    const int n0g  = (blockIdx.x >> 2) * 64;       // global row in [0, 8192)
    const int b    = n0g >> 11;
    const int n0   = n0g & (NDIM - 1);
    const int bh   = b * 4 + head;

    __shared__ __align__(16) __bf16 Wl[64][LP];    // 17.4 KB
    __shared__ __align__(16) __bf16 Xl[64][LP];    // 17.4 KB

    // fused adj pack: this block covers int4 indices [blk*2048, blk*2048+2048)
    int4 ap[8];
    #pragma unroll
    for (int i = 0; i < 8; ++i)
        ap[i] = ((const int4*)adj)[blockIdx.x * 2048 + i * 256 + t];

    #pragma unroll
    for (int i = 0; i < 8; ++i) {
        int idx = t + i * 256;
        int r = idx >> 5, c4 = idx & 31;
        float4 wv = *((const float4*)(W + (size_t)(head * 64 + r) * 128) + c4);
        bf16x4 bv;
        bv[0] = (__bf16)wv.x; bv[1] = (__bf16)wv.y; bv[2] = (__bf16)wv.z; bv[3] = (__bf16)wv.w;
        *(bf16x4*)&Wl[r][c4 * 4] = bv;
    }
    #pragma unroll
    for (int i = 0; i < 8; ++i) {
        int idx = t + i * 256;
        int r = idx >> 5, c4 = idx & 31;
        float4 xv = *((const float4*)(x + (size_t)(n0g + r) * 128) + c4);
        bf16x4 bv;
        bv[0] = (__bf16)xv.x; bv[1] = (__bf16)xv.y; bv[2] = (__bf16)xv.z; bv[3] = (__bf16)xv.w;
        *(bf16x4*)&Xl[r][c4 * 4] = bv;
    }

    // pack + store bits (overlaps staging latency / MFMA issue)
    #pragma unroll
    for (int i = 0; i < 8; ++i) {
        int q = blockIdx.x * 2048 + i * 256 + t;
        unsigned nib = (unsigned)(ap[i].x > 0) | ((unsigned)(ap[i].y > 0) << 1) |
                       ((unsigned)(ap[i].z > 0) << 2) | ((unsigned)(ap[i].w > 0) << 3);
        unsigned v = nib << ((t & 7) * 4);
        v |= __shfl_xor(v, 1, 64);
        v |= __shfl_xor(v, 2, 64);
        v |= __shfl_xor(v, 4, 64);
        if ((t & 7) == 0) bits[q >> 3] = v;
    }
    __syncthreads();

    const int lane = t & 63, w = t >> 6;
    const int m = lane & 15, q4 = lane >> 4;

    bf16x8 bfr[4];
    #pragma unroll
    for (int ks = 0; ks < 4; ++ks)
        bfr[ks] = *(const bf16x8*)&Xl[w * 16 + m][ks * 32 + q4 * 8];

    f32x4 acc[4];
    #pragma unroll
    for (int c = 0; c < 4; ++c) acc[c] = (f32x4){0.f, 0.f, 0.f, 0.f};

    #pragma unroll
    for (int ct = 0; ct < 4; ++ct) {
        #pragma unroll
        for (int ks = 0; ks < 4; ++ks) {
            bf16x8 afr = *(const bf16x8*)&Wl[ct * 16 + m][ks * 32 + q4 * 8];
            acc[ct] = __builtin_amdgcn_mfma_f32_16x16x32_bf16(afr, bfr[ks], acc[ct], 0, 0, 0);
        }
    }

    const int nloc = n0 + w * 16 + m;
    float esA = 0.f, edA = 0.f;
    #pragma unroll
    for (int ct = 0; ct < 4; ++ct) {
        float4 aS = *(const float4*)(att_src + head * 64 + ct * 16 + q4 * 4);
        float4 aD = *(const float4*)(att_dst + head * 64 + ct * 16 + q4 * 4);
        #pragma unroll
        for (int r = 0; r < 4; ++r) {
            float v = acc[ct][r];
            int   d = ct * 16 + q4 * 4 + r;
            h_t[(size_t)(bh * 64 + d) * NDIM + nloc] = (__bf16)v;
            esA += v * ((const float*)&aS)[r];
            edA += v * ((const float*)&aD)[r];
        }
    }
    esA += __shfl_xor(esA, 16, 64); esA += __shfl_xor(esA, 32, 64);
    edA += __shfl_xor(edA, 16, 64); edA += __shfl_xor(edA, 32, 64);
    if (lane < 16) {
        es_ws[bh * NDIM + nloc] = esA * LOG2E;   // pre-scaled: exp2 domain
        ed_ws[bh * NDIM + nloc] = edA * LOG2E;
    }
}

// ---------------- attention: 32x32x16 PV, DMA-staged Hl, register p-gen -------
// grid 256: bh = blk & 15, i0 = (blk>>4)*128. Wave w owns i-rows i0+w*32+m32.
// Hl[buf][d][64] bf16 swizzled: chunk c8 of row d holds j-chunk (c8 ^ (d&7)).
__global__ __launch_bounds__(256) void gat_attn(
    const unsigned long long* __restrict__ bits, const __bf16* __restrict__ h_t,
    const float* __restrict__ es_ws, const float* __restrict__ ed_ws,
    float* __restrict__ out)
{
    const int blk = blockIdx.x;
    const int bh  = blk & 15;
    const int i0  = (blk >> 4) * 128;
    const int t   = threadIdx.x;
    const int lane = t & 63, w = t >> 6;
    const int m32 = lane & 31, q = lane >> 5;     // q in {0,1}
    const int sw  = m32 & 7;

    __shared__ __align__(16) __bf16 Hl[2][64][64];   // 16 KB

    // DMA staging (identical scheme to R4): wave w stages rows w*16..w*16+15
    const int r0 = w * 16 + (lane >> 3);
    const int r1 = r0 + 8;
    const int c8 = lane & 7;
    const __bf16* g0 = h_t + ((size_t)(bh * 64 + r0)) * NDIM + ((c8 ^ (r0 & 7)) * 8);
    const __bf16* g1 = h_t + ((size_t)(bh * 64 + r1)) * NDIM + ((c8 ^ (r1 & 7)) * 8);
    __bf16* l0a = &Hl[0][r0][c8 * 8];
    __bf16* l0b = &Hl[0][r1][c8 * 8];
    __bf16* l1a = &Hl[1][r0][c8 * 8];
    __bf16* l1b = &Hl[1][r1][c8 * 8];

    const int irow = i0 + w * 32 + m32;
    const float es2 = es_ws[bh * NDIM + irow];                  // *log2e already
    const unsigned long long* brow = bits + (size_t)irow * 32;
    const float* edp = ed_ws + bh * NDIM + q * 8;               // *log2e already

    // preload tile 0
    load_lds16(g0, l0a);
    load_lds16(g1, l0b);
    float eb[2][32] __attribute__((aligned(16)));
    unsigned long long bwb[2];
    #pragma unroll
    for (int ks = 0; ks < 4; ++ks) {
        *(float4*)&eb[0][ks * 8]     = *(const float4*)(edp + ks * 16);
        *(float4*)&eb[0][ks * 8 + 4] = *(const float4*)(edp + ks * 16 + 4);
    }
    bwb[0] = brow[0];

    f32x16 acc0 = {0.f}, acc1 = {0.f}, accl = {0.f};
    #pragma unroll
    for (int e = 0; e < 16; ++e) { acc0[e] = 0.f; acc1[e] = 0.f; accl[e] = 0.f; }
    bf16x8 ones;
    #pragma unroll
    for (int jj = 0; jj < 8; ++jj) ones[jj] = (__bf16)1.0f;

    __syncthreads();    // drains tile-0 DMA

#define STEP(ITJ, P)                                                            \
    {                                                                           \
        const int itj = (ITJ);                                                  \
        if (itj < 31) {                                                         \
            load_lds16(g0 + (itj + 1) * 64, (P) ? l0a : l1a);                   \
            load_lds16(g1 + (itj + 1) * 64, (P) ? l0b : l1b);                   \
            const float* ep = edp + (itj + 1) * 64;                             \
            _Pragma("unroll")                                                   \
            for (int ks = 0; ks < 4; ++ks) {                                    \
                *(float4*)&eb[(P) ^ 1][ks * 8]     = *(const float4*)(ep + ks * 16);     \
                *(float4*)&eb[(P) ^ 1][ks * 8 + 4] = *(const float4*)(ep + ks * 16 + 4); \
            }                                                                   \
            bwb[(P) ^ 1] = brow[itj + 1];                                       \
        }                                                                       \
        bf16x8 af[4];                                                           \
        _Pragma("unroll")                                                       \
        for (int ks = 0; ks < 4; ++ks) {                                        \
            unsigned bm = (unsigned)(bwb[P] >> (ks * 16 + q * 8)) & 0xFFu;      \
            _Pragma("unroll")                                                   \
            for (int jj = 0; jj < 8; ++jj) {                                    \
                float s = es2 + eb[P][ks * 8 + jj];                             \
                s = fmaxf(s, NEG_SLOPE * s);                                    \
                s = ((bm >> jj) & 1u) ? s : -10000.0f;                          \
                af[ks][jj] = (__bf16)__builtin_amdgcn_exp2f(s);                 \
            }                                                                   \
        }                                                                       \
        _Pragma("unroll")                                                       \
        for (int ks = 0; ks < 4; ++ks) {                                        \
            accl = __builtin_amdgcn_mfma_f32_32x32x16_bf16(af[ks], ones, accl, 0, 0, 0); \
            bf16x8 b0 = *(const bf16x8*)&Hl[P][m32][(((ks * 2 + q) ^ sw)) * 8];          \
            acc0 = __builtin_amdgcn_mfma_f32_32x32x16_bf16(af[ks], b0, acc0, 0, 0, 0);   \
            bf16x8 b1 = *(const bf16x8*)&Hl[P][32 + m32][(((ks * 2 + q) ^ sw)) * 8];     \
            acc1 = __builtin_amdgcn_mfma_f32_32x32x16_bf16(af[ks], b1, acc1, 0, 0, 0);   \
        }                                                                       \
        __syncthreads();                                                        \
    }

    for (int it2 = 0; it2 < 16; ++it2) {
        STEP(it2 * 2, 0);
        STEP(it2 * 2 + 1, 1);
    }
#undef STEP

    // C layout (verified): col = lane&31, row = (reg&3) + 8*(reg>>2) + 4*q.
    // accl has the same mapping -> per-reg normalize, no shuffles.
    const int b = bh >> 2, head = bh & 3;
    #pragma unroll
    for (int reg = 0; reg < 16; ++reg) {
        const int r = (reg & 3) + 8 * (reg >> 2) + 4 * q;
        const float inv = 1.f / accl[reg];
        float* op = out + ((size_t)(b * NDIM + i0 + w * 32 + r)) * 256 + head * 64 + m32;
        op[0]  = acc0[reg] * inv;
        op[32] = acc1[reg] * inv;
    }
}

extern "C" void kernel_launch(void* const* d_in, const int* in_sizes, int n_in,
                              void* d_out, int out_size, void* d_ws, size_t ws_size,
                              hipStream_t stream) {
    const float* x       = (const float*)d_in[0];
    const int*   adj     = (const int*)d_in[1];
    const float* W       = (const float*)d_in[2];
    const float* att_src = (const float*)d_in[3];
    const float* att_dst = (const float*)d_in[4];
    float* out = (float*)d_out;

    __bf16*   h_t   = (__bf16*)d_ws;                              // 4 MB
    float*    es_ws = (float*)((char*)d_ws + (size_t)4 * 1024 * 1024);
    float*    ed_ws = es_ws + 16 * NDIM;                          // 128 KB each
    unsigned* bitsp = (unsigned*)(ed_ws + 16 * NDIM);             // 512 KB

    gat_linear<<<512, 256, 0, stream>>>(x, W, att_src, att_dst, adj, bitsp,
                                        h_t, es_ws, ed_ws);
    gat_attn<<<256, 256, 0, stream>>>((const unsigned long long*)bitsp,
                                      h_t, es_ws, ed_ws, out);
}

// Round 6
// 108.886 us; speedup vs baseline: 1.0366x; 1.0366x over previous
//
#include <hip/hip_runtime.h>

// GAT: B=4, N=2048, IN_DIM=128, H=4, D=64.
// R6 = R4 (best measured): separate adj_pack; linear with n-contiguous h_t
// stores + pre-scaled (log2e) es/ed; attn with global_load_lds-staged
// XOR-swizzled Hl double-buffer, register p-gen (exp2), ones-MFMA row sums.
// R5's 32x32 PV + adj-fusion reverted: B-frag LDS volume is invariant per
// wave (full H), so 32x32 only added l-MFMA issue cycles; adj fusion delayed
// linear and raised VGPR pressure.

#define NDIM 2048
#define NEG_SLOPE 0.2f
#define LOG2E 1.4426950408889634f

typedef __bf16 bf16x8 __attribute__((ext_vector_type(8)));
typedef __bf16 bf16x4 __attribute__((ext_vector_type(4)));
typedef float  f32x4  __attribute__((ext_vector_type(4)));

#define LP 136   // linear LDS pitch (bf16)

__device__ static inline void load_lds16(const void* g, void* l) {
    __builtin_amdgcn_global_load_lds(
        (const __attribute__((address_space(1))) unsigned*)g,
        (__attribute__((address_space(3))) unsigned*)l, 16, 0, 0);
}

// ---------------- adj -> bitmask (bit k of word w = adj[w*32+k]) ----------------
__global__ __launch_bounds__(256) void adj_pack(const int* __restrict__ adj,
                                                unsigned* __restrict__ bits) {
    const int t = threadIdx.x;
    const int q = blockIdx.x * 256 + t;            // int4 index
    int4 a = ((const int4*)adj)[q];
    unsigned nib = (unsigned)(a.x > 0) | ((unsigned)(a.y > 0) << 1) |
                   ((unsigned)(a.z > 0) << 2) | ((unsigned)(a.w > 0) << 3);
    unsigned v = nib << ((t & 7) * 4);
    v |= __shfl_xor(v, 1, 64);
    v |= __shfl_xor(v, 2, 64);
    v |= __shfl_xor(v, 4, 64);
    if ((t & 7) == 0) bits[q >> 3] = v;
}

// ---------------- linear: h = x @ W^T (A=W rows -> C rows = out-channel) --------
__global__ __launch_bounds__(256) void gat_linear(
    const float* __restrict__ x, const float* __restrict__ W,
    const float* __restrict__ att_src, const float* __restrict__ att_dst,
    __bf16* __restrict__ h_t, float* __restrict__ es_ws, float* __restrict__ ed_ws)
{
    const int t    = threadIdx.x;
    const int head = blockIdx.x & 3;
    const int n0g  = (blockIdx.x >> 2) * 64;       // global row in [0, 8192)
    const int b    = n0g >> 11;
    const int n0   = n0g & (NDIM - 1);
    const int bh   = b * 4 + head;

    __shared__ __align__(16) __bf16 Wl[64][LP];    // 17.4 KB
    __shared__ __align__(16) __bf16 Xl[64][LP];    // 17.4 KB

    #pragma unroll
    for (int i = 0; i < 8; ++i) {
        int idx = t + i * 256;
        int r = idx >> 5, c4 = idx & 31;
        float4 wv = *((const float4*)(W + (size_t)(head * 64 + r) * 128) + c4);
        bf16x4 bv;
        bv[0] = (__bf16)wv.x; bv[1] = (__bf16)wv.y; bv[2] = (__bf16)wv.z; bv[3] = (__bf16)wv.w;
        *(bf16x4*)&Wl[r][c4 * 4] = bv;
    }
    #pragma unroll
    for (int i = 0; i < 8; ++i) {
        int idx = t + i * 256;
        int r = idx >> 5, c4 = idx & 31;
        float4 xv = *((const float4*)(x + (size_t)(n0g + r) * 128) + c4);
        bf16x4 bv;
        bv[0] = (__bf16)xv.x; bv[1] = (__bf16)xv.y; bv[2] = (__bf16)xv.z; bv[3] = (__bf16)xv.w;
        *(bf16x4*)&Xl[r][c4 * 4] = bv;
    }
    __syncthreads();

    const int lane = t & 63, w = t >> 6;
    const int m = lane & 15, q4 = lane >> 4;

    bf16x8 bfr[4];
    #pragma unroll
    for (int ks = 0; ks < 4; ++ks)
        bfr[ks] = *(const bf16x8*)&Xl[w * 16 + m][ks * 32 + q4 * 8];

    f32x4 acc[4];
    #pragma unroll
    for (int c = 0; c < 4; ++c) acc[c] = (f32x4){0.f, 0.f, 0.f, 0.f};

    #pragma unroll
    for (int ct = 0; ct < 4; ++ct) {
        #pragma unroll
        for (int ks = 0; ks < 4; ++ks) {
            bf16x8 afr = *(const bf16x8*)&Wl[ct * 16 + m][ks * 32 + q4 * 8];
            acc[ct] = __builtin_amdgcn_mfma_f32_16x16x32_bf16(afr, bfr[ks], acc[ct], 0, 0, 0);
        }
    }

    // epilogue: h_t[bh][d][n] (n-contiguous) + es/ed reductions over d
    const int nloc = n0 + w * 16 + m;
    float esA = 0.f, edA = 0.f;
    #pragma unroll
    for (int ct = 0; ct < 4; ++ct) {
        float4 aS = *(const float4*)(att_src + head * 64 + ct * 16 + q4 * 4);
        float4 aD = *(const float4*)(att_dst + head * 64 + ct * 16 + q4 * 4);
        #pragma unroll
        for (int r = 0; r < 4; ++r) {
            float v = acc[ct][r];
            int   d = ct * 16 + q4 * 4 + r;
            h_t[(size_t)(bh * 64 + d) * NDIM + nloc] = (__bf16)v;
            esA += v * ((const float*)&aS)[r];
            edA += v * ((const float*)&aD)[r];
        }
    }
    esA += __shfl_xor(esA, 16, 64); esA += __shfl_xor(esA, 32, 64);
    edA += __shfl_xor(edA, 16, 64); edA += __shfl_xor(edA, 32, 64);
    if (lane < 16) {
        es_ws[bh * NDIM + nloc] = esA * LOG2E;   // pre-scaled: exp2 domain
        ed_ws[bh * NDIM + nloc] = edA * LOG2E;
    }
}

// ---------------- attention: DMA-staged Hl + register p-gen + MFMA PV ----------
// grid 512: bh = blk & 15, it = blk >> 4. Wave w owns A-rows i0+w*16+m.
// Hl[buf][d][64] bf16, XOR-swizzled: chunk c8 of row d holds j-chunk (c8 ^ (d&7)).
__global__ __launch_bounds__(256) void gat_attn(
    const unsigned long long* __restrict__ bits, const __bf16* __restrict__ h_t,
    const float* __restrict__ es_ws, const float* __restrict__ ed_ws,
    float* __restrict__ out)
{
    const int blk = blockIdx.x;
    const int bh  = blk & 15;
    const int i0  = (blk >> 4) * 64;
    const int t   = threadIdx.x;
    const int lane = t & 63, w = t >> 6;
    const int m = lane & 15, q4 = lane >> 4;

    __shared__ __align__(16) __bf16 Hl[2][64][64];   // 16 KB

    // DMA lanes: wave w stages rows w*16..w*16+15 (2 chunks of 8 rows)
    const int r0 = w * 16 + (lane >> 3);
    const int r1 = r0 + 8;
    const int c8 = lane & 7;
    const __bf16* g0 = h_t + ((size_t)(bh * 64 + r0)) * NDIM + ((c8 ^ (r0 & 7)) * 8);
    const __bf16* g1 = h_t + ((size_t)(bh * 64 + r1)) * NDIM + ((c8 ^ (r1 & 7)) * 8);
    __bf16* l0a = &Hl[0][r0][c8 * 8];
    __bf16* l0b = &Hl[0][r1][c8 * 8];
    __bf16* l1a = &Hl[1][r0][c8 * 8];
    __bf16* l1b = &Hl[1][r1][c8 * 8];

    const float es2 = es_ws[bh * NDIM + i0 + w * 16 + m];       // *log2e already
    const unsigned long long* brow = bits + (size_t)(i0 + w * 16 + m) * 32;
    const float* edp = ed_ws + bh * NDIM + q4 * 8;              // *log2e already

    // preload tile 0: DMA + scalar prefetch
    load_lds16(g0, l0a);
    load_lds16(g1, l0b);
    float eb[2][16];
    unsigned long long bwb[2];
    #pragma unroll
    for (int g = 0; g < 4; ++g)
        *(float4*)&eb[0][g * 4] = *(const float4*)(edp + (g >> 1) * 32 + (g & 1) * 4);
    bwb[0] = brow[0];

    f32x4 acc[4], accl;
    #pragma unroll
    for (int c = 0; c < 4; ++c) acc[c] = (f32x4){0.f, 0.f, 0.f, 0.f};
    accl = (f32x4){0.f, 0.f, 0.f, 0.f};
    bf16x8 ones;
    #pragma unroll
    for (int jj = 0; jj < 8; ++jj) ones[jj] = (__bf16)1.0f;
    const int sw = m & 7;

    __syncthreads();    // drains tile-0 DMA

#define STEP(ITJ, P)                                                            \
    {                                                                           \
        const int itj = (ITJ);                                                  \
        if (itj < 31) {                                                         \
            load_lds16(g0 + (itj + 1) * 64, (P) ? l0a : l1a);                   \
            load_lds16(g1 + (itj + 1) * 64, (P) ? l0b : l1b);                   \
            const float* ep = edp + (itj + 1) * 64;                             \
            _Pragma("unroll")                                                   \
            for (int g = 0; g < 4; ++g)                                         \
                *(float4*)&eb[(P) ^ 1][g * 4] =                                 \
                    *(const float4*)(ep + (g >> 1) * 32 + (g & 1) * 4);         \
            bwb[(P) ^ 1] = brow[itj + 1];                                       \
        }                                                                       \
        bf16x8 af[2];                                                           \
        _Pragma("unroll")                                                       \
        for (int ks = 0; ks < 2; ++ks) {                                        \
            unsigned bm = (unsigned)(bwb[P] >> (ks * 32 + q4 * 8)) & 0xFFu;     \
            _Pragma("unroll")                                                   \
            for (int jj = 0; jj < 8; ++jj) {                                    \
                float s = es2 + eb[P][ks * 8 + jj];                             \
                s = fmaxf(s, NEG_SLOPE * s);                                    \
                s = ((bm >> jj) & 1u) ? s : -10000.0f;                          \
                af[ks][jj] = (__bf16)__builtin_amdgcn_exp2f(s);                 \
            }                                                                   \
        }                                                                       \
        _Pragma("unroll")                                                       \
        for (int ks = 0; ks < 2; ++ks) {                                        \
            accl = __builtin_amdgcn_mfma_f32_16x16x32_bf16(af[ks], ones, accl, 0, 0, 0); \
            _Pragma("unroll")                                                   \
            for (int ct = 0; ct < 4; ++ct) {                                    \
                bf16x8 bfr = *(const bf16x8*)&Hl[P][ct * 16 + m][(((ks * 4 + q4) ^ sw)) * 8]; \
                acc[ct] = __builtin_amdgcn_mfma_f32_16x16x32_bf16(af[ks], bfr, acc[ct], 0, 0, 0); \
            }                                                                   \
        }                                                                       \
        __syncthreads();                                                        \
    }

    for (int it2 = 0; it2 < 16; ++it2) {
        STEP(it2 * 2, 0);
        STEP(it2 * 2 + 1, 1);
    }
#undef STEP

    // accl[r] = l for output row q4*4+r (all m-lanes identical) — no shuffles
    float invr[4];
    #pragma unroll
    for (int r = 0; r < 4; ++r) invr[r] = 1.f / accl[r];

    const int b = bh >> 2, head = bh & 3;
    float* ob = out + ((size_t)(b * NDIM + i0 + w * 16)) * 256 + head * 64;
    #pragma unroll
    for (int ct = 0; ct < 4; ++ct) {
        #pragma unroll
        for (int r = 0; r < 4; ++r) {
            ob[(size_t)(q4 * 4 + r) * 256 + ct * 16 + m] = acc[ct][r] * invr[r];
        }
    }
}

extern "C" void kernel_launch(void* const* d_in, const int* in_sizes, int n_in,
                              void* d_out, int out_size, void* d_ws, size_t ws_size,
                              hipStream_t stream) {
    const float* x       = (const float*)d_in[0];
    const int*   adj     = (const int*)d_in[1];
    const float* W       = (const float*)d_in[2];
    const float* att_src = (const float*)d_in[3];
    const float* att_dst = (const float*)d_in[4];
    float* out = (float*)d_out;

    __bf16*   h_t   = (__bf16*)d_ws;                              // 4 MB
    float*    es_ws = (float*)((char*)d_ws + (size_t)4 * 1024 * 1024);
    float*    ed_ws = es_ws + 16 * NDIM;                          // 128 KB each
    unsigned* bitsp = (unsigned*)(ed_ws + 16 * NDIM);             // 512 KB

    adj_pack<<<NDIM * NDIM / 4 / 256, 256, 0, stream>>>(adj, bitsp);
    gat_linear<<<512, 256, 0, stream>>>(x, W, att_src, att_dst, h_t, es_ws, ed_ws);
    gat_attn<<<512, 256, 0, stream>>>((const unsigned long long*)bitsp, h_t, es_ws, ed_ws, out);
}